// Round 2
// 1781.171 us; speedup vs baseline: 1.7823x; 1.7823x over previous
//
#include <hip/hip_runtime.h>
#include <math.h>

#define NNODES 10000
#define NEDGES 160000
#define EN_TOT (NNODES + NEDGES)  // 170000
#define NBLK 79                   // ceil(10000/128)
#define NTRI 3160                 // NBLK*(NBLK+1)/2, divisible by 8

typedef __attribute__((ext_vector_type(8))) short bf16x8;
typedef __attribute__((ext_vector_type(4))) float f32x4;
typedef __attribute__((address_space(1))) const void g_void;
typedef __attribute__((address_space(3))) void l_void;

// ---------- helpers ----------
static __device__ __forceinline__ unsigned enc_f(float f) {
    unsigned b = __float_as_uint(f);
    return (b & 0x80000000u) ? ~b : (b | 0x80000000u);  // order-preserving float->uint
}
static __device__ __forceinline__ float dec_f(unsigned u) {
    unsigned b = (u & 0x80000000u) ? (u & 0x7FFFFFFFu) : ~u;
    return __uint_as_float(b);
}
static __device__ __forceinline__ unsigned short f2bf(float f) {
    unsigned u = __float_as_uint(f);
    return (unsigned short)((u + 0x7FFFu + ((u >> 16) & 1u)) >> 16);  // RNE
}

// ---------- generic fp32 GEMM: C = act(A[M,K] @ W[K,N] + bias) ----------
__global__ __launch_bounds__(256) void gemm64(
    const float* __restrict__ A, const float* __restrict__ B,
    const float* __restrict__ bias, float* __restrict__ C,
    int M, int K, int Nn, int act) {
    __shared__ float As[16][68];
    __shared__ float Bs[16][68];
    int tid = threadIdx.x;
    int tx = tid & 15, ty = tid >> 4;
    int row0 = blockIdx.y * 64, col0 = blockIdx.x * 64;
    float acc[4][4] = {};
    for (int k0 = 0; k0 < K; k0 += 16) {
        int r = tid >> 2, c4 = (tid & 3) << 2;
        float4 av = make_float4(0.f, 0.f, 0.f, 0.f);
        if (row0 + r < M) av = *(const float4*)&A[(size_t)(row0 + r) * K + k0 + c4];
        As[c4 + 0][r] = av.x; As[c4 + 1][r] = av.y; As[c4 + 2][r] = av.z; As[c4 + 3][r] = av.w;
        int kk = tid >> 4, n4 = (tid & 15) << 2;
        *(float4*)&Bs[kk][n4] = *(const float4*)&B[(size_t)(k0 + kk) * Nn + col0 + n4];
        __syncthreads();
#pragma unroll
        for (int k2 = 0; k2 < 16; k2++) {
            float4 a4 = *(float4*)&As[k2][ty * 4];
            float4 b4 = *(float4*)&Bs[k2][tx * 4];
            float aa[4] = {a4.x, a4.y, a4.z, a4.w};
            float bb[4] = {b4.x, b4.y, b4.z, b4.w};
#pragma unroll
            for (int i = 0; i < 4; i++)
#pragma unroll
                for (int j = 0; j < 4; j++) acc[i][j] += aa[i] * bb[j];
        }
        __syncthreads();
    }
#pragma unroll
    for (int i = 0; i < 4; i++) {
        int gm = row0 + ty * 4 + i;
        if (gm >= M) continue;
        float4 v;
        float* vp = &v.x;
#pragma unroll
        for (int j = 0; j < 4; j++) {
            float t = acc[i][j];
            if (bias) t += bias[col0 + tx * 4 + j];
            if (act) t = fmaxf(t, 0.f);
            vp[j] = t;
        }
        *(float4*)&C[(size_t)gm * Nn + col0 + tx * 4] = v;
    }
}

// ---------- GAT attention scores per node: als/ald [N,2] ----------
__global__ __launch_bounds__(128) void gat_scores(
    const float* __restrict__ h, const float* __restrict__ a_src,
    const float* __restrict__ a_dst, float* __restrict__ als, float* __restrict__ ald) {
    int n = blockIdx.x;
    int w = threadIdx.x >> 6;  // head
    int l = threadIdx.x & 63;
    const float* hp = h + (size_t)n * 1024 + w * 512 + l * 8;
    const float* asp = a_src + w * 512 + l * 8;
    const float* adp = a_dst + w * 512 + l * 8;
    float s = 0.f, d = 0.f;
#pragma unroll
    for (int i = 0; i < 8; i++) { float hv = hp[i]; s += hv * asp[i]; d += hv * adp[i]; }
#pragma unroll
    for (int off = 32; off; off >>= 1) { s += __shfl_down(s, off); d += __shfl_down(d, off); }
    if (l == 0) { als[n * 2 + w] = s; ald[n * 2 + w] = d; }
}

// ---------- CSR build ----------
__global__ void k_count(const int* __restrict__ ei, int* __restrict__ cnt) {
    int e = blockIdx.x * blockDim.x + threadIdx.x;
    if (e >= EN_TOT) return;
    int d = (e < NEDGES) ? ei[NEDGES + e] : (e - NEDGES);
    atomicAdd(&cnt[d], 1);
}

__global__ __launch_bounds__(256) void k_scan(
    const int* __restrict__ cnt, int* __restrict__ rowstart,
    int* __restrict__ cursor, float* __restrict__ dinv) {
    __shared__ int buf[256];
    __shared__ int carry;
    int t = threadIdx.x;
    if (t == 0) carry = 0;
    __syncthreads();
    for (int base = 0; base < NNODES; base += 256) {
        int i = base + t;
        int v = (i < NNODES) ? cnt[i] : 0;
        buf[t] = v;
        __syncthreads();
        for (int off = 1; off < 256; off <<= 1) {
            int x = (t >= off) ? buf[t - off] : 0;
            __syncthreads();
            buf[t] += x;
            __syncthreads();
        }
        int incl = buf[t];
        int cbase = carry;
        if (i < NNODES) {
            int rs = cbase + incl - v;
            rowstart[i] = rs;
            cursor[i] = rs;
            dinv[i] = (v > 0) ? rsqrtf((float)v) : 0.f;
        }
        __syncthreads();
        if (t == 255) carry = cbase + incl;
        __syncthreads();
    }
    if (t == 0) rowstart[NNODES] = carry;
}

__global__ void k_fill(const int* __restrict__ ei, int* __restrict__ cursor,
                       int* __restrict__ csr_src, int* __restrict__ csr_eid) {
    int e = blockIdx.x * blockDim.x + threadIdx.x;
    if (e >= EN_TOT) return;
    int s, d;
    if (e < NEDGES) { s = ei[e]; d = ei[NEDGES + e]; } else { s = e - NEDGES; d = s; }
    int pos = atomicAdd(&cursor[d], 1);
    csr_src[pos] = s;
    csr_eid[pos] = e;
}

// ---------- GAT softmax over incoming edges ----------
__global__ void k_init_gat(unsigned* __restrict__ emax, float* __restrict__ esum) {
    int i = blockIdx.x * blockDim.x + threadIdx.x;
    if (i < NNODES * 2) { emax[i] = 0x007FFFFFu; esum[i] = 0.f; }
}

__global__ void k_edge_score(const int* __restrict__ ei, const float* __restrict__ als,
                             const float* __restrict__ ald, float* __restrict__ score,
                             unsigned* __restrict__ emax) {
    int e = blockIdx.x * blockDim.x + threadIdx.x;
    if (e >= EN_TOT) return;
    int s, d;
    if (e < NEDGES) { s = ei[e]; d = ei[NEDGES + e]; } else { s = e - NEDGES; d = s; }
#pragma unroll
    for (int h = 0; h < 2; h++) {
        float v = als[s * 2 + h] + ald[d * 2 + h];
        v = (v > 0.f) ? v : 0.2f * v;  // leaky_relu 0.2
        score[e * 2 + h] = v;
        atomicMax(&emax[d * 2 + h], enc_f(v));
    }
}

__global__ void k_edge_exp(const int* __restrict__ ei, float* __restrict__ score,
                           const unsigned* __restrict__ emax, float* __restrict__ esum) {
    int e = blockIdx.x * blockDim.x + threadIdx.x;
    if (e >= EN_TOT) return;
    int d = (e < NEDGES) ? ei[NEDGES + e] : (e - NEDGES);
#pragma unroll
    for (int h = 0; h < 2; h++) {
        float m = dec_f(emax[d * 2 + h]);
        float x = expf(score[e * 2 + h] - m);
        score[e * 2 + h] = x;
        atomicAdd(&esum[d * 2 + h], x);
    }
}

// ---------- GAT aggregation (gather over CSR): out[n,1024] ----------
__global__ __launch_bounds__(256) void gat_aggregate(
    const float* __restrict__ hfeat, const float* __restrict__ ex,
    const float* __restrict__ esum, const int* __restrict__ rowstart,
    const int* __restrict__ csr_src, const int* __restrict__ csr_eid,
    const float* __restrict__ bias, float* __restrict__ out, int act) {
    int n = blockIdx.x;
    int t = threadIdx.x;
    int c0 = t * 4;
    int head = c0 >> 9;
    float inv = 1.f / (esum[n * 2 + head] + 1e-16f);
    int beg = rowstart[n], end = rowstart[n + 1];
    float4 acc = make_float4(0.f, 0.f, 0.f, 0.f);
    for (int p = beg; p < end; p++) {
        int s = csr_src[p];
        int eid = csr_eid[p];
        float alpha = ex[eid * 2 + head] * inv;
        float4 hv = *(const float4*)&hfeat[(size_t)s * 1024 + c0];
        acc.x += alpha * hv.x; acc.y += alpha * hv.y;
        acc.z += alpha * hv.z; acc.w += alpha * hv.w;
    }
    float4 bv = *(const float4*)&bias[c0];
    acc.x += bv.x; acc.y += bv.y; acc.z += bv.z; acc.w += bv.w;
    if (act) {
        acc.x = fmaxf(acc.x, 0.f); acc.y = fmaxf(acc.y, 0.f);
        acc.z = fmaxf(acc.z, 0.f); acc.w = fmaxf(acc.w, 0.f);
    }
    *(float4*)&out[(size_t)n * 1024 + c0] = acc;
}

// ---------- GCN aggregation (gather over CSR): out[n,512] ----------
__global__ __launch_bounds__(128) void gcn_aggregate(
    const float* __restrict__ hfeat, const float* __restrict__ dinv,
    const int* __restrict__ rowstart, const int* __restrict__ csr_src,
    const float* __restrict__ bias, float* __restrict__ out, int act) {
    int n = blockIdx.x;
    int t = threadIdx.x;
    int c0 = t * 4;
    float dn = dinv[n];
    int beg = rowstart[n], end = rowstart[n + 1];
    float4 acc = make_float4(0.f, 0.f, 0.f, 0.f);
    for (int p = beg; p < end; p++) {
        int s = csr_src[p];
        float w = dinv[s] * dn;
        float4 hv = *(const float4*)&hfeat[(size_t)s * 512 + c0];
        acc.x += w * hv.x; acc.y += w * hv.y; acc.z += w * hv.z; acc.w += w * hv.w;
    }
    float4 bv = *(const float4*)&bias[c0];
    acc.x += bv.x; acc.y += bv.y; acc.z += bv.z; acc.w += bv.w;
    if (act) {
        acc.x = fmaxf(acc.x, 0.f); acc.y = fmaxf(acc.y, 0.f);
        acc.z = fmaxf(acc.z, 0.f); acc.w = fmaxf(acc.w, 0.f);
    }
    *(float4*)&out[(size_t)n * 512 + c0] = acc;
}

// ---------- split fp32 -> (bf16 hi, bf16 lo) in BLOCKED staging layout ----------
// G[nb][kc][r][8]: nb = node-block of 128, kc = k-chunk of 8 (128 total),
// r = row within block. This is byte-identical to the LDS layout k_gram_pdist
// stages, so its global_load_lds reads become fully contiguous/coalesced.
// Padded rows (node >= NNODES) are written as zeros.
__global__ __launch_bounds__(256) void k_split_blk(
    const float* __restrict__ X, unsigned short* __restrict__ Ghi,
    unsigned short* __restrict__ Glo) {
    __shared__ float T[128][69];  // 64-col tile, odd-ish stride vs banks
    const int nb = blockIdx.y;   // node block
    const int ct = blockIdx.x;   // 64-column tile (8 k-chunks)
    const int t = threadIdx.x;
    // phase 1: load X[nb*128 + r][ct*64 + c] (coalesced) into T
#pragma unroll
    for (int it = 0; it < 8; it++) {
        int idx = it * 256 + t;        // 0..2047
        int r = idx >> 4;              // 0..127
        int c4 = (idx & 15) << 2;      // 0..60
        int node = nb * 128 + r;
        float4 v = make_float4(0.f, 0.f, 0.f, 0.f);
        if (node < NNODES) v = *(const float4*)&X[(size_t)node * 1024 + ct * 64 + c4];
        T[r][c4 + 0] = v.x; T[r][c4 + 1] = v.y; T[r][c4 + 2] = v.z; T[r][c4 + 3] = v.w;
    }
    __syncthreads();
    // phase 2: each thread emits one 16B hi piece + one 16B lo piece, coalesced
#pragma unroll
    for (int it = 0; it < 4; it++) {
        int idx = it * 256 + t;        // 0..1023
        int kcl = idx >> 7;            // 0..7 local k-chunk
        int r = idx & 127;
        int kc = ct * 8 + kcl;         // global k-chunk 0..127
        size_t go = (((size_t)nb * 128 + kc) * 128 + r) * 8;
        unsigned hv[4], lv[4];
#pragma unroll
        for (int p = 0; p < 4; p++) {
            float f0 = T[r][kcl * 8 + 2 * p];
            float f1 = T[r][kcl * 8 + 2 * p + 1];
            unsigned short h0 = f2bf(f0), h1 = f2bf(f1);
            unsigned short l0 = f2bf(f0 - __uint_as_float((unsigned)h0 << 16));
            unsigned short l1 = f2bf(f1 - __uint_as_float((unsigned)h1 << 16));
            hv[p] = (unsigned)h0 | ((unsigned)h1 << 16);
            lv[p] = (unsigned)l0 | ((unsigned)l1 << 16);
        }
        *(uint4*)&Ghi[go] = make_uint4(hv[0], hv[1], hv[2], hv[3]);
        *(uint4*)&Glo[go] = make_uint4(lv[0], lv[1], lv[2], lv[3]);
    }
}

// ---------- squared norms ----------
__global__ __launch_bounds__(256) void k_sqn(const float* __restrict__ X,
                                             float* __restrict__ sqn) {
    __shared__ float wsum[4];
    int n = blockIdx.x;
    int t = threadIdx.x;
    float4 v = *(const float4*)&X[(size_t)n * 1024 + t * 4];
    float s = v.x * v.x + v.y * v.y + v.z * v.z + v.w * v.w;
#pragma unroll
    for (int off = 32; off; off >>= 1) s += __shfl_down(s, off);
    if ((t & 63) == 0) wsum[t >> 6] = s;
    __syncthreads();
    if (t == 0) sqn[n] = wsum[0] + wsum[1] + wsum[2] + wsum[3];
}

// ---------- pdist via bf16-split MFMA Gram + norms ----------
// Triangular grid (bi<=bj): each block computes a 128x128 tile and writes it
// plus its mirror. Staging reads are contiguous 8KB-per-wave thanks to the
// blocked G layout. Output stores are non-temporal so the 400MB stream does
// not evict the 41MB G dataset from L2/L3.
__global__ __launch_bounds__(256) void k_gram_pdist(
    const unsigned short* __restrict__ Ghi, const unsigned short* __restrict__ Glo,
    const float* __restrict__ sq, float* __restrict__ out) {
    __shared__ unsigned short lds[16384];  // 4 x 8KB
    const int tid = threadIdx.x;
    const int lane = tid & 63;
    const int w = tid >> 6;  // wave id == staged matrix id

    // XCD-bijective swizzle (NTRI % 8 == 0) + triangular decode
    int bid = blockIdx.x;
    int u = (bid & 7) * (NTRI / 8) + (bid >> 3);
    int bi = (int)((double)NBLK + 0.5 - sqrt(((double)NBLK + 0.5) * ((double)NBLK + 0.5) - 2.0 * (double)u));
    if (bi < 0) bi = 0;
    if (bi > NBLK - 1) bi = NBLK - 1;
    auto cum = [](int r) { return r * NBLK - (r * (r - 1)) / 2; };
    while (bi + 1 <= NBLK - 1 && cum(bi + 1) <= u) bi++;
    while (bi > 0 && cum(bi) > u) bi--;
    const int bj = bi + (u - cum(bi));
    const int row0 = bi * 128;
    const int col0 = bj * 128;
    const int wr = w >> 1, wc = w & 1;

    // matrix 0: hi@row-block, 1: lo@row-block, 2: hi@col-block, 3: lo@col-block
    const unsigned short* mat = (w & 1) ? Glo : Ghi;
    const int nbq = (w < 2) ? bi : bj;
    const unsigned short* base = mat + (size_t)nbq * 131072;  // 128kc*128r*8

    f32x4 acc[4][4];
#pragma unroll
    for (int i = 0; i < 4; i++)
#pragma unroll
        for (int j = 0; j < 4; j++) acc[i][j] = (f32x4){0.f, 0.f, 0.f, 0.f};

    const int q = lane >> 4;   // frag k-chunk
    const int r16 = lane & 15;

    for (int kc0 = 0; kc0 < 128; kc0 += 4) {
        // stage: 8 x 1KB contiguous global_load_lds per wave (wave w -> matrix w)
        const unsigned short* gp0 = base + (size_t)kc0 * 1024;
#pragma unroll
        for (int s = 0; s < 8; s++) {
            const unsigned short* gp = gp0 + s * 512 + lane * 8;
            unsigned short* lp = &lds[w * 4096 + s * 512];  // wave-uniform
            __builtin_amdgcn_global_load_lds((g_void*)gp, (l_void*)lp, 16, 0, 0);
        }
        __syncthreads();

        bf16x8 ah[4], al[4], bh[4], bl[4];
#pragma unroll
        for (int t = 0; t < 4; t++) {
            int aoff = q * 1024 + (wr * 64 + t * 16 + r16) * 8;
            ah[t] = *(const bf16x8*)&lds[aoff];
            al[t] = *(const bf16x8*)&lds[4096 + aoff];
            int boff = q * 1024 + (wc * 64 + t * 16 + r16) * 8;
            bh[t] = *(const bf16x8*)&lds[8192 + boff];
            bl[t] = *(const bf16x8*)&lds[12288 + boff];
        }
#pragma unroll
        for (int i = 0; i < 4; i++)
#pragma unroll
            for (int j = 0; j < 4; j++) {
                acc[i][j] = __builtin_amdgcn_mfma_f32_16x16x32_bf16(ah[i], bh[j], acc[i][j], 0, 0, 0);
                acc[i][j] = __builtin_amdgcn_mfma_f32_16x16x32_bf16(ah[i], bl[j], acc[i][j], 0, 0, 0);
                acc[i][j] = __builtin_amdgcn_mfma_f32_16x16x32_bf16(al[i], bh[j], acc[i][j], 0, 0, 0);
            }
        __syncthreads();
    }

    // epilogue: d = sqrt(max(sq_i + sq_j - 2G, 0)); diagonal forced to 0.
    // Forward tile (row-block bi, col-block bj): scalar nt stores.
    // Mirror tile: lane's 4 column values are 4 consecutive cols -> f32x4 nt store.
    const int q4 = (lane >> 4) << 2;
    float sqj[4];
    int gj[4];
#pragma unroll
    for (int j = 0; j < 4; j++) {
        gj[j] = col0 + wc * 64 + j * 16 + r16;
        sqj[j] = (gj[j] < NNODES) ? sq[gj[j]] : 0.f;
    }
#pragma unroll
    for (int i = 0; i < 4; i++) {
        int gibase = row0 + wr * 64 + i * 16 + q4;
        bool iv = gibase < NNODES;  // NNODES%4==0 -> all-or-nothing per 4-group
        float4 sqi = iv ? *(const float4*)&sq[gibase] : make_float4(0.f, 0.f, 0.f, 0.f);
        float* sqip = &sqi.x;
#pragma unroll
        for (int j = 0; j < 4; j++) {
            if (!iv || gj[j] >= NNODES) continue;
            float dv[4];
#pragma unroll
            for (int r = 0; r < 4; r++) {
                float d2 = sqip[r] + sqj[j] - 2.f * acc[i][j][r];
                float d = sqrtf(fmaxf(d2, 0.f));
                if (gibase + r == gj[j]) d = 0.f;
                dv[r] = d;
            }
#pragma unroll
            for (int r = 0; r < 4; r++)
                __builtin_nontemporal_store(dv[r], &out[(size_t)(gibase + r) * NNODES + gj[j]]);
            f32x4 mv = {dv[0], dv[1], dv[2], dv[3]};
            __builtin_nontemporal_store(mv, (f32x4*)&out[(size_t)gj[j] * NNODES + gibase]);
        }
    }
}

// ---------- launch ----------
extern "C" void kernel_launch(void* const* d_in, const int* in_sizes, int n_in,
                              void* d_out, int out_size, void* d_ws, size_t ws_size,
                              hipStream_t stream) {
    const float* x            = (const float*)d_in[0];
    const int*   ei           = (const int*)d_in[1];
    const float* enc_gat_W    = (const float*)d_in[2];
    const float* enc_gat_asrc = (const float*)d_in[3];
    const float* enc_gat_adst = (const float*)d_in[4];
    const float* enc_gat_b    = (const float*)d_in[5];
    const float* enc_gcn_W    = (const float*)d_in[6];
    const float* enc_gcn_b    = (const float*)d_in[7];
    const float* densea_W     = (const float*)d_in[8];
    const float* densea_b     = (const float*)d_in[9];
    const float* latent_W     = (const float*)d_in[10];
    const float* latent_b     = (const float*)d_in[11];
    const float* dec1_W       = (const float*)d_in[12];
    const float* dec1_b       = (const float*)d_in[13];
    const float* dec2_W       = (const float*)d_in[14];
    const float* dec2_b       = (const float*)d_in[15];
    const float* dec_gcn_W    = (const float*)d_in[16];
    const float* dec_gcn_b    = (const float*)d_in[17];
    const float* dec_gat_W    = (const float*)d_in[18];
    const float* dec_gat_asrc = (const float*)d_in[19];
    const float* dec_gat_adst = (const float*)d_in[20];
    const float* dec_gat_b    = (const float*)d_in[21];

    float* out = (float*)d_out;

    // ws layout (~45 MB): blocked split matrices must survive pdist.
    // per-matrix size: NBLK*128kc*128r*8 = 10,354,688 ushorts
    const size_t GSZ = (size_t)NBLK * 131072;
    unsigned short* Xhi = (unsigned short*)d_ws;
    unsigned short* Xlo = Xhi + GSZ;
    float*    sqn      = (float*)(Xlo + GSZ);      // 10,000
    float*    score    = sqn + 10000;              // EN*2 = 340,000
    float*    esum     = score + 340000;           // 20,000
    unsigned* emax     = (unsigned*)(esum + 20000);
    float*    als      = (float*)(emax + 20000);
    float*    ald      = als + 20000;
    int*      cnt      = (int*)(ald + 20000);
    int*      cursor   = cnt + 10000;
    int*      rowstart = cursor + 10000;           // 10,001
    float*    dinv     = (float*)(rowstart + 10001);
    int*      csr_src  = (int*)(dinv + 10000);     // 170,000
    int*      csr_eid  = csr_src + 170000;         // 170,000

    // big intermediates live in d_out (overwritten by pdist at the end)
    float* bufA = out;             // N*1024
    float* bufB = out + 10500000;  // N*1024  (also decoder-GAT output / pre-split feat)
    float* bufC = out + 21000000;  // N*512
    float* bufD = out + 26500000;  // N*512
    float* h128 = out + 32000000;  // N*128
    float* z64  = out + 33500000;  // N*64
    float* d128 = out + 34500000;  // N*128

    const int NT = 256;
    dim3 eb((EN_TOT + NT - 1) / NT);

    hipMemsetAsync(cnt, 0, NNODES * sizeof(int), stream);
    k_count<<<eb, NT, 0, stream>>>(ei, cnt);
    k_scan<<<1, 256, 0, stream>>>(cnt, rowstart, cursor, dinv);
    k_fill<<<eb, NT, 0, stream>>>(ei, cursor, csr_src, csr_eid);

    auto gemm = [&](const float* A, const float* W, const float* bias, float* Cc,
                    int M, int K, int Nn, int act) {
        dim3 g(Nn / 64, (M + 63) / 64);
        gemm64<<<g, 256, 0, stream>>>(A, W, bias, Cc, M, K, Nn, act);
    };

    // ----- encoder GAT -----
    gemm(x, enc_gat_W, nullptr, bufA, NNODES, 512, 1024, 0);
    gat_scores<<<NNODES, 128, 0, stream>>>(bufA, enc_gat_asrc, enc_gat_adst, als, ald);
    k_init_gat<<<(2 * NNODES + 255) / 256, 256, 0, stream>>>(emax, esum);
    k_edge_score<<<eb, NT, 0, stream>>>(ei, als, ald, score, emax);
    k_edge_exp<<<eb, NT, 0, stream>>>(ei, score, emax, esum);
    gat_aggregate<<<NNODES, 256, 0, stream>>>(bufA, score, esum, rowstart, csr_src,
                                              csr_eid, enc_gat_b, bufB, 1);

    // ----- encoder GCN -----
    gemm(bufB, enc_gcn_W, nullptr, bufC, NNODES, 1024, 512, 0);
    gcn_aggregate<<<NNODES, 128, 0, stream>>>(bufC, dinv, rowstart, csr_src,
                                              enc_gcn_b, bufD, 1);

    // ----- dense encoder / decoder -----
    gemm(bufD, densea_W, densea_b, h128, NNODES, 512, 128, 1);
    gemm(h128, latent_W, latent_b, z64, NNODES, 128, 64, 0);
    gemm(z64, dec1_W, dec1_b, d128, NNODES, 64, 128, 1);
    gemm(d128, dec2_W, dec2_b, bufC, NNODES, 128, 512, 1);

    // ----- decoder GCN -----
    gemm(bufC, dec_gcn_W, nullptr, bufD, NNODES, 512, 512, 0);
    gcn_aggregate<<<NNODES, 128, 0, stream>>>(bufD, dinv, rowstart, csr_src,
                                              dec_gcn_b, bufC, 1);

    // ----- decoder GAT (no relu) -> bufB -----
    gemm(bufC, dec_gat_W, nullptr, bufA, NNODES, 512, 1024, 0);
    gat_scores<<<NNODES, 128, 0, stream>>>(bufA, dec_gat_asrc, dec_gat_adst, als, ald);
    k_init_gat<<<(2 * NNODES + 255) / 256, 256, 0, stream>>>(emax, esum);
    k_edge_score<<<eb, NT, 0, stream>>>(ei, als, ald, score, emax);
    k_edge_exp<<<eb, NT, 0, stream>>>(ei, score, emax, esum);
    gat_aggregate<<<NNODES, 256, 0, stream>>>(bufA, score, esum, rowstart, csr_src,
                                              csr_eid, dec_gat_b, bufB, 0);

    // ----- blocked split + norms, then triangular MFMA pdist -----
    dim3 sg(16, NBLK);
    k_split_blk<<<sg, 256, 0, stream>>>(bufB, Xhi, Xlo);
    k_sqn<<<NNODES, 256, 0, stream>>>(bufB, sqn);
    k_gram_pdist<<<NTRI, 256, 0, stream>>>(Xhi, Xlo, sqn, out);
}

// Round 3
// 1460.108 us; speedup vs baseline: 2.1742x; 1.2199x over previous
//
#include <hip/hip_runtime.h>
#include <math.h>

#define NNODES 10000
#define NEDGES 160000
#define EN_TOT (NNODES + NEDGES)  // 170000
#define NBLK 79                   // ceil(10000/128)
#define NTRI 3160                 // NBLK*(NBLK+1)/2, divisible by 8

typedef __attribute__((ext_vector_type(8))) short bf16x8;
typedef __attribute__((ext_vector_type(4))) float f32x4;
typedef __attribute__((address_space(1))) const void g_void;
typedef __attribute__((address_space(3))) void l_void;

// ---------- helpers ----------
static __device__ __forceinline__ unsigned enc_f(float f) {
    unsigned b = __float_as_uint(f);
    return (b & 0x80000000u) ? ~b : (b | 0x80000000u);  // order-preserving float->uint
}
static __device__ __forceinline__ float dec_f(unsigned u) {
    unsigned b = (u & 0x80000000u) ? (u & 0x7FFFFFFFu) : ~u;
    return __uint_as_float(b);
}
static __device__ __forceinline__ unsigned short f2bf(float f) {
    unsigned u = __float_as_uint(f);
    return (unsigned short)((u + 0x7FFFu + ((u >> 16) & 1u)) >> 16);  // RNE
}

// ---------- generic fp32 GEMM (small layers only) ----------
__global__ __launch_bounds__(256) void gemm64(
    const float* __restrict__ A, const float* __restrict__ B,
    const float* __restrict__ bias, float* __restrict__ C,
    int M, int K, int Nn, int act) {
    __shared__ float As[16][68];
    __shared__ float Bs[16][68];
    int tid = threadIdx.x;
    int tx = tid & 15, ty = tid >> 4;
    int row0 = blockIdx.y * 64, col0 = blockIdx.x * 64;
    float acc[4][4] = {};
    for (int k0 = 0; k0 < K; k0 += 16) {
        int r = tid >> 2, c4 = (tid & 3) << 2;
        float4 av = make_float4(0.f, 0.f, 0.f, 0.f);
        if (row0 + r < M) av = *(const float4*)&A[(size_t)(row0 + r) * K + k0 + c4];
        As[c4 + 0][r] = av.x; As[c4 + 1][r] = av.y; As[c4 + 2][r] = av.z; As[c4 + 3][r] = av.w;
        int kk = tid >> 4, n4 = (tid & 15) << 2;
        *(float4*)&Bs[kk][n4] = *(const float4*)&B[(size_t)(k0 + kk) * Nn + col0 + n4];
        __syncthreads();
#pragma unroll
        for (int k2 = 0; k2 < 16; k2++) {
            float4 a4 = *(float4*)&As[k2][ty * 4];
            float4 b4 = *(float4*)&Bs[k2][tx * 4];
            float aa[4] = {a4.x, a4.y, a4.z, a4.w};
            float bb[4] = {b4.x, b4.y, b4.z, b4.w};
#pragma unroll
            for (int i = 0; i < 4; i++)
#pragma unroll
                for (int j = 0; j < 4; j++) acc[i][j] += aa[i] * bb[j];
        }
        __syncthreads();
    }
#pragma unroll
    for (int i = 0; i < 4; i++) {
        int gm = row0 + ty * 4 + i;
        if (gm >= M) continue;
        float4 v;
        float* vp = &v.x;
#pragma unroll
        for (int j = 0; j < 4; j++) {
            float t = acc[i][j];
            if (bias) t += bias[col0 + tx * 4 + j];
            if (act) t = fmaxf(t, 0.f);
            vp[j] = t;
        }
        *(float4*)&C[(size_t)gm * Nn + col0 + tx * 4] = v;
    }
}

// ---------- GAT attention scores per node: als/ald [N,2] ----------
__global__ __launch_bounds__(128) void gat_scores(
    const float* __restrict__ h, const float* __restrict__ a_src,
    const float* __restrict__ a_dst, float* __restrict__ als, float* __restrict__ ald) {
    int n = blockIdx.x;
    int w = threadIdx.x >> 6;  // head
    int l = threadIdx.x & 63;
    const float* hp = h + (size_t)n * 1024 + w * 512 + l * 8;
    const float* asp = a_src + w * 512 + l * 8;
    const float* adp = a_dst + w * 512 + l * 8;
    float s = 0.f, d = 0.f;
#pragma unroll
    for (int i = 0; i < 8; i++) { float hv = hp[i]; s += hv * asp[i]; d += hv * adp[i]; }
#pragma unroll
    for (int off = 32; off; off >>= 1) { s += __shfl_down(s, off); d += __shfl_down(d, off); }
    if (l == 0) { als[n * 2 + w] = s; ald[n * 2 + w] = d; }
}

// ---------- CSR build ----------
__global__ void k_count(const int* __restrict__ ei, int* __restrict__ cnt) {
    int e = blockIdx.x * blockDim.x + threadIdx.x;
    if (e >= EN_TOT) return;
    int d = (e < NEDGES) ? ei[NEDGES + e] : (e - NEDGES);
    atomicAdd(&cnt[d], 1);
}

__global__ __launch_bounds__(256) void k_scan(
    const int* __restrict__ cnt, int* __restrict__ rowstart,
    int* __restrict__ cursor, float* __restrict__ dinv) {
    __shared__ int buf[256];
    __shared__ int carry;
    int t = threadIdx.x;
    if (t == 0) carry = 0;
    __syncthreads();
    for (int base = 0; base < NNODES; base += 256) {
        int i = base + t;
        int v = (i < NNODES) ? cnt[i] : 0;
        buf[t] = v;
        __syncthreads();
        for (int off = 1; off < 256; off <<= 1) {
            int x = (t >= off) ? buf[t - off] : 0;
            __syncthreads();
            buf[t] += x;
            __syncthreads();
        }
        int incl = buf[t];
        int cbase = carry;
        if (i < NNODES) {
            int rs = cbase + incl - v;
            rowstart[i] = rs;
            cursor[i] = rs;
            dinv[i] = (v > 0) ? rsqrtf((float)v) : 0.f;
        }
        __syncthreads();
        if (t == 255) carry = cbase + incl;
        __syncthreads();
    }
    if (t == 0) rowstart[NNODES] = carry;
}

__global__ void k_fill(const int* __restrict__ ei, int* __restrict__ cursor,
                       int* __restrict__ csr_src, int* __restrict__ csr_eid) {
    int e = blockIdx.x * blockDim.x + threadIdx.x;
    if (e >= EN_TOT) return;
    int s, d;
    if (e < NEDGES) { s = ei[e]; d = ei[NEDGES + e]; } else { s = e - NEDGES; d = s; }
    int pos = atomicAdd(&cursor[d], 1);
    csr_src[pos] = s;
    csr_eid[pos] = e;
}

// ---------- GAT softmax over incoming edges ----------
__global__ void k_init_gat(unsigned* __restrict__ emax, float* __restrict__ esum) {
    int i = blockIdx.x * blockDim.x + threadIdx.x;
    if (i < NNODES * 2) { emax[i] = 0x007FFFFFu; esum[i] = 0.f; }
}

__global__ void k_edge_score(const int* __restrict__ ei, const float* __restrict__ als,
                             const float* __restrict__ ald, float* __restrict__ score,
                             unsigned* __restrict__ emax) {
    int e = blockIdx.x * blockDim.x + threadIdx.x;
    if (e >= EN_TOT) return;
    int s, d;
    if (e < NEDGES) { s = ei[e]; d = ei[NEDGES + e]; } else { s = e - NEDGES; d = s; }
#pragma unroll
    for (int h = 0; h < 2; h++) {
        float v = als[s * 2 + h] + ald[d * 2 + h];
        v = (v > 0.f) ? v : 0.2f * v;  // leaky_relu 0.2
        score[e * 2 + h] = v;
        atomicMax(&emax[d * 2 + h], enc_f(v));
    }
}

__global__ void k_edge_exp(const int* __restrict__ ei, float* __restrict__ score,
                           const unsigned* __restrict__ emax, float* __restrict__ esum) {
    int e = blockIdx.x * blockDim.x + threadIdx.x;
    if (e >= EN_TOT) return;
    int d = (e < NEDGES) ? ei[NEDGES + e] : (e - NEDGES);
#pragma unroll
    for (int h = 0; h < 2; h++) {
        float m = dec_f(emax[d * 2 + h]);
        float x = expf(score[e * 2 + h] - m);
        score[e * 2 + h] = x;
        atomicAdd(&esum[d * 2 + h], x);
    }
}

// ---------- GAT aggregation (gather over CSR): out[n,1024] ----------
__global__ __launch_bounds__(256) void gat_aggregate(
    const float* __restrict__ hfeat, const float* __restrict__ ex,
    const float* __restrict__ esum, const int* __restrict__ rowstart,
    const int* __restrict__ csr_src, const int* __restrict__ csr_eid,
    const float* __restrict__ bias, float* __restrict__ out, int act) {
    int n = blockIdx.x;
    int t = threadIdx.x;
    int c0 = t * 4;
    int head = c0 >> 9;
    float inv = 1.f / (esum[n * 2 + head] + 1e-16f);
    int beg = rowstart[n], end = rowstart[n + 1];
    float4 acc = make_float4(0.f, 0.f, 0.f, 0.f);
    for (int p = beg; p < end; p++) {
        int s = csr_src[p];
        int eid = csr_eid[p];
        float alpha = ex[eid * 2 + head] * inv;
        float4 hv = *(const float4*)&hfeat[(size_t)s * 1024 + c0];
        acc.x += alpha * hv.x; acc.y += alpha * hv.y;
        acc.z += alpha * hv.z; acc.w += alpha * hv.w;
    }
    float4 bv = *(const float4*)&bias[c0];
    acc.x += bv.x; acc.y += bv.y; acc.z += bv.z; acc.w += bv.w;
    if (act) {
        acc.x = fmaxf(acc.x, 0.f); acc.y = fmaxf(acc.y, 0.f);
        acc.z = fmaxf(acc.z, 0.f); acc.w = fmaxf(acc.w, 0.f);
    }
    *(float4*)&out[(size_t)n * 1024 + c0] = acc;
}

// ---------- GCN aggregation (gather over CSR): out[n,512] ----------
__global__ __launch_bounds__(128) void gcn_aggregate(
    const float* __restrict__ hfeat, const float* __restrict__ dinv,
    const int* __restrict__ rowstart, const int* __restrict__ csr_src,
    const float* __restrict__ bias, float* __restrict__ out, int act) {
    int n = blockIdx.x;
    int t = threadIdx.x;
    int c0 = t * 4;
    float dn = dinv[n];
    int beg = rowstart[n], end = rowstart[n + 1];
    float4 acc = make_float4(0.f, 0.f, 0.f, 0.f);
    for (int p = beg; p < end; p++) {
        int s = csr_src[p];
        float w = dinv[s] * dn;
        float4 hv = *(const float4*)&hfeat[(size_t)s * 512 + c0];
        acc.x += w * hv.x; acc.y += w * hv.y; acc.z += w * hv.z; acc.w += w * hv.w;
    }
    float4 bv = *(const float4*)&bias[c0];
    acc.x += bv.x; acc.y += bv.y; acc.z += bv.z; acc.w += bv.w;
    if (act) {
        acc.x = fmaxf(acc.x, 0.f); acc.y = fmaxf(acc.y, 0.f);
        acc.z = fmaxf(acc.z, 0.f); acc.w = fmaxf(acc.w, 0.f);
    }
    *(float4*)&out[(size_t)n * 512 + c0] = acc;
}

// ---------- split fp32 [NNODES,K] -> (bf16 hi, bf16 lo) BLOCKED layout ----------
// G[nb][kc][r][8]: nb = node-block of 128, kc = k-chunk of 8 (KC = K/8 total),
// r = row within block. Byte-identical to the LDS tile the MFMA kernels stage,
// so global_load_lds reads are fully contiguous. Padded rows -> zeros.
__global__ __launch_bounds__(256) void k_split_blk(
    const float* __restrict__ X, unsigned short* __restrict__ Ghi,
    unsigned short* __restrict__ Glo, int K) {
    __shared__ float T[128][69];  // 64-col tile
    const int nb = blockIdx.y;   // node block
    const int ct = blockIdx.x;   // 64-column tile (8 k-chunks)
    const int t = threadIdx.x;
    const int KC = K >> 3;
    // phase 1: load X[nb*128 + r][ct*64 + c] (coalesced) into T
#pragma unroll
    for (int it = 0; it < 8; it++) {
        int idx = it * 256 + t;        // 0..2047
        int r = idx >> 4;              // 0..127
        int c4 = (idx & 15) << 2;      // 0..60
        int node = nb * 128 + r;
        float4 v = make_float4(0.f, 0.f, 0.f, 0.f);
        if (node < NNODES) v = *(const float4*)&X[(size_t)node * K + ct * 64 + c4];
        T[r][c4 + 0] = v.x; T[r][c4 + 1] = v.y; T[r][c4 + 2] = v.z; T[r][c4 + 3] = v.w;
    }
    __syncthreads();
    // phase 2: each thread emits one 16B hi piece + one 16B lo piece, coalesced
#pragma unroll
    for (int it = 0; it < 4; it++) {
        int idx = it * 256 + t;        // 0..1023
        int kcl = idx >> 7;            // 0..7 local k-chunk
        int r = idx & 127;
        int kc = ct * 8 + kcl;         // global k-chunk
        size_t go = (((size_t)nb * KC + kc) * 128 + r) * 8;
        unsigned hv[4], lv[4];
#pragma unroll
        for (int p = 0; p < 4; p++) {
            float f0 = T[r][kcl * 8 + 2 * p];
            float f1 = T[r][kcl * 8 + 2 * p + 1];
            unsigned short h0 = f2bf(f0), h1 = f2bf(f1);
            unsigned short l0 = f2bf(f0 - __uint_as_float((unsigned)h0 << 16));
            unsigned short l1 = f2bf(f1 - __uint_as_float((unsigned)h1 << 16));
            hv[p] = (unsigned)h0 | ((unsigned)h1 << 16);
            lv[p] = (unsigned)l0 | ((unsigned)l1 << 16);
        }
        *(uint4*)&Ghi[go] = make_uint4(hv[0], hv[1], hv[2], hv[3]);
        *(uint4*)&Glo[go] = make_uint4(lv[0], lv[1], lv[2], lv[3]);
    }
}

// ---------- split weights W[K][N] transposed -> blocked Wt[cb][kc][c][8] ----------
// B-operand layout: lane holds Wt[col][k0..k0+7] = W[k0..k0+7][col].
// Requires N % 128 == 0, K % 16 == 0. Grid: (KC/2, N/128), 256 thr.
__global__ __launch_bounds__(256) void k_splitw(
    const float* __restrict__ W, unsigned short* __restrict__ Whi,
    unsigned short* __restrict__ Wlo, int K, int N) {
    const int cb = blockIdx.y;
    const int t = threadIdx.x;
    const int c = t & 127;
    const int kc = blockIdx.x * 2 + (t >> 7);
    const int col = cb * 128 + c;
    const int KC = K >> 3;
    unsigned hv[4], lv[4];
#pragma unroll
    for (int p = 0; p < 4; p++) {
        float f0 = W[(size_t)(kc * 8 + 2 * p) * N + col];
        float f1 = W[(size_t)(kc * 8 + 2 * p + 1) * N + col];
        unsigned short h0 = f2bf(f0), h1 = f2bf(f1);
        unsigned short l0 = f2bf(f0 - __uint_as_float((unsigned)h0 << 16));
        unsigned short l1 = f2bf(f1 - __uint_as_float((unsigned)h1 << 16));
        hv[p] = (unsigned)h0 | ((unsigned)h1 << 16);
        lv[p] = (unsigned)l0 | ((unsigned)l1 << 16);
    }
    size_t go = (((size_t)cb * KC + kc) * 128 + c) * 8;
    *(uint4*)&Whi[go] = make_uint4(hv[0], hv[1], hv[2], hv[3]);
    *(uint4*)&Wlo[go] = make_uint4(lv[0], lv[1], lv[2], lv[3]);
}

// ---------- bf16-split MFMA GEMM: C = act(A[M,K] @ W[K,N] + bias) ----------
// Same structure as k_gram_pdist: 128x128 tile, 4 waves (2x2), split-3
// (hh+hl+lh). A from blocked AHi/ALo (node blocks), B from blocked WtHi/WtLo
// (col blocks). Grid: (N/128, NBLK).
__global__ __launch_bounds__(256) void gemm_mfma(
    const unsigned short* __restrict__ AHi, const unsigned short* __restrict__ ALo,
    const unsigned short* __restrict__ BHi, const unsigned short* __restrict__ BLo,
    const float* __restrict__ bias, float* __restrict__ C,
    int KC, int N, int act) {
    __shared__ unsigned short lds[16384];  // 4 x 8KB
    const int tid = threadIdx.x;
    const int lane = tid & 63;
    const int w = tid >> 6;
    const int bi = blockIdx.y;  // row (node) block
    const int bj = blockIdx.x;  // col block
    const int wr = w >> 1, wc = w & 1;

    // wave 0: AHi@bi, 1: ALo@bi, 2: BHi@bj, 3: BLo@bj
    const unsigned short* mat = (w < 2) ? ((w & 1) ? ALo : AHi) : ((w & 1) ? BLo : BHi);
    const int nbq = (w < 2) ? bi : bj;
    const unsigned short* base = mat + (size_t)nbq * KC * 1024;

    f32x4 acc[4][4];
#pragma unroll
    for (int i = 0; i < 4; i++)
#pragma unroll
        for (int j = 0; j < 4; j++) acc[i][j] = (f32x4){0.f, 0.f, 0.f, 0.f};

    const int q = lane >> 4;
    const int r16 = lane & 15;

    for (int kc0 = 0; kc0 < KC; kc0 += 4) {
        const unsigned short* gp0 = base + (size_t)kc0 * 1024;
#pragma unroll
        for (int s = 0; s < 8; s++) {
            const unsigned short* gp = gp0 + s * 512 + lane * 8;
            unsigned short* lp = &lds[w * 4096 + s * 512];  // wave-uniform
            __builtin_amdgcn_global_load_lds((g_void*)gp, (l_void*)lp, 16, 0, 0);
        }
        __syncthreads();

        bf16x8 ah[4], al[4], bh[4], bl[4];
#pragma unroll
        for (int t = 0; t < 4; t++) {
            int aoff = q * 1024 + (wr * 64 + t * 16 + r16) * 8;
            ah[t] = *(const bf16x8*)&lds[aoff];
            al[t] = *(const bf16x8*)&lds[4096 + aoff];
            int boff = q * 1024 + (wc * 64 + t * 16 + r16) * 8;
            bh[t] = *(const bf16x8*)&lds[8192 + boff];
            bl[t] = *(const bf16x8*)&lds[12288 + boff];
        }
#pragma unroll
        for (int i = 0; i < 4; i++)
#pragma unroll
            for (int j = 0; j < 4; j++) {
                acc[i][j] = __builtin_amdgcn_mfma_f32_16x16x32_bf16(ah[i], bh[j], acc[i][j], 0, 0, 0);
                acc[i][j] = __builtin_amdgcn_mfma_f32_16x16x32_bf16(ah[i], bl[j], acc[i][j], 0, 0, 0);
                acc[i][j] = __builtin_amdgcn_mfma_f32_16x16x32_bf16(al[i], bh[j], acc[i][j], 0, 0, 0);
            }
        __syncthreads();
    }

    // epilogue: bias + optional relu, fp32 row-major store
    const int q4 = (lane >> 4) << 2;
    float bv[4];
    int gj[4];
#pragma unroll
    for (int j = 0; j < 4; j++) {
        gj[j] = bj * 128 + wc * 64 + j * 16 + r16;
        bv[j] = bias ? bias[gj[j]] : 0.f;
    }
#pragma unroll
    for (int i = 0; i < 4; i++) {
        int gibase = bi * 128 + wr * 64 + i * 16 + q4;
        if (gibase >= NNODES) continue;  // NNODES%4==0 -> all-or-nothing per group
#pragma unroll
        for (int j = 0; j < 4; j++) {
#pragma unroll
            for (int r = 0; r < 4; r++) {
                float t = acc[i][j][r] + bv[j];
                if (act) t = fmaxf(t, 0.f);
                C[(size_t)(gibase + r) * N + gj[j]] = t;
            }
        }
    }
}

// ---------- squared norms ----------
__global__ __launch_bounds__(256) void k_sqn(const float* __restrict__ X,
                                             float* __restrict__ sqn) {
    __shared__ float wsum[4];
    int n = blockIdx.x;
    int t = threadIdx.x;
    float4 v = *(const float4*)&X[(size_t)n * 1024 + t * 4];
    float s = v.x * v.x + v.y * v.y + v.z * v.z + v.w * v.w;
#pragma unroll
    for (int off = 32; off; off >>= 1) s += __shfl_down(s, off);
    if ((t & 63) == 0) wsum[t >> 6] = s;
    __syncthreads();
    if (t == 0) sqn[n] = wsum[0] + wsum[1] + wsum[2] + wsum[3];
}

// ---------- pdist via bf16-split MFMA Gram + norms ----------
__global__ __launch_bounds__(256) void k_gram_pdist(
    const unsigned short* __restrict__ Ghi, const unsigned short* __restrict__ Glo,
    const float* __restrict__ sq, float* __restrict__ out) {
    __shared__ unsigned short lds[16384];  // 4 x 8KB
    const int tid = threadIdx.x;
    const int lane = tid & 63;
    const int w = tid >> 6;  // wave id == staged matrix id

    // XCD-bijective swizzle (NTRI % 8 == 0) + triangular decode
    int bid = blockIdx.x;
    int u = (bid & 7) * (NTRI / 8) + (bid >> 3);
    int bi = (int)((double)NBLK + 0.5 - sqrt(((double)NBLK + 0.5) * ((double)NBLK + 0.5) - 2.0 * (double)u));
    if (bi < 0) bi = 0;
    if (bi > NBLK - 1) bi = NBLK - 1;
    auto cum = [](int r) { return r * NBLK - (r * (r - 1)) / 2; };
    while (bi + 1 <= NBLK - 1 && cum(bi + 1) <= u) bi++;
    while (bi > 0 && cum(bi) > u) bi--;
    const int bj = bi + (u - cum(bi));
    const int row0 = bi * 128;
    const int col0 = bj * 128;
    const int wr = w >> 1, wc = w & 1;

    // matrix 0: hi@row-block, 1: lo@row-block, 2: hi@col-block, 3: lo@col-block
    const unsigned short* mat = (w & 1) ? Glo : Ghi;
    const int nbq = (w < 2) ? bi : bj;
    const unsigned short* base = mat + (size_t)nbq * 131072;  // 128kc*128r*8

    f32x4 acc[4][4];
#pragma unroll
    for (int i = 0; i < 4; i++)
#pragma unroll
        for (int j = 0; j < 4; j++) acc[i][j] = (f32x4){0.f, 0.f, 0.f, 0.f};

    const int q = lane >> 4;   // frag k-chunk
    const int r16 = lane & 15;

    for (int kc0 = 0; kc0 < 128; kc0 += 4) {
        const unsigned short* gp0 = base + (size_t)kc0 * 1024;
#pragma unroll
        for (int s = 0; s < 8; s++) {
            const unsigned short* gp = gp0 + s * 512 + lane * 8;
            unsigned short* lp = &lds[w * 4096 + s * 512];  // wave-uniform
            __builtin_amdgcn_global_load_lds((g_void*)gp, (l_void*)lp, 16, 0, 0);
        }
        __syncthreads();

        bf16x8 ah[4], al[4], bh[4], bl[4];
#pragma unroll
        for (int t = 0; t < 4; t++) {
            int aoff = q * 1024 + (wr * 64 + t * 16 + r16) * 8;
            ah[t] = *(const bf16x8*)&lds[aoff];
            al[t] = *(const bf16x8*)&lds[4096 + aoff];
            int boff = q * 1024 + (wc * 64 + t * 16 + r16) * 8;
            bh[t] = *(const bf16x8*)&lds[8192 + boff];
            bl[t] = *(const bf16x8*)&lds[12288 + boff];
        }
#pragma unroll
        for (int i = 0; i < 4; i++)
#pragma unroll
            for (int j = 0; j < 4; j++) {
                acc[i][j] = __builtin_amdgcn_mfma_f32_16x16x32_bf16(ah[i], bh[j], acc[i][j], 0, 0, 0);
                acc[i][j] = __builtin_amdgcn_mfma_f32_16x16x32_bf16(ah[i], bl[j], acc[i][j], 0, 0, 0);
                acc[i][j] = __builtin_amdgcn_mfma_f32_16x16x32_bf16(al[i], bh[j], acc[i][j], 0, 0, 0);
            }
        __syncthreads();
    }

    // epilogue: d = sqrt(max(sq_i + sq_j - 2G, 0)); diagonal forced to 0.
    const int q4 = (lane >> 4) << 2;
    float sqj[4];
    int gj[4];
#pragma unroll
    for (int j = 0; j < 4; j++) {
        gj[j] = col0 + wc * 64 + j * 16 + r16;
        sqj[j] = (gj[j] < NNODES) ? sq[gj[j]] : 0.f;
    }
#pragma unroll
    for (int i = 0; i < 4; i++) {
        int gibase = row0 + wr * 64 + i * 16 + q4;
        bool iv = gibase < NNODES;  // NNODES%4==0 -> all-or-nothing per 4-group
        float4 sqi = iv ? *(const float4*)&sq[gibase] : make_float4(0.f, 0.f, 0.f, 0.f);
        float* sqip = &sqi.x;
#pragma unroll
        for (int j = 0; j < 4; j++) {
            if (!iv || gj[j] >= NNODES) continue;
            float dv[4];
#pragma unroll
            for (int r = 0; r < 4; r++) {
                float d2 = sqip[r] + sqj[j] - 2.f * acc[i][j][r];
                float d = sqrtf(fmaxf(d2, 0.f));
                if (gibase + r == gj[j]) d = 0.f;
                dv[r] = d;
            }
#pragma unroll
            for (int r = 0; r < 4; r++)
                __builtin_nontemporal_store(dv[r], &out[(size_t)(gibase + r) * NNODES + gj[j]]);
            f32x4 mv = {dv[0], dv[1], dv[2], dv[3]};
            __builtin_nontemporal_store(mv, (f32x4*)&out[(size_t)gj[j] * NNODES + gibase]);
        }
    }
}

// ---------- launch ----------
extern "C" void kernel_launch(void* const* d_in, const int* in_sizes, int n_in,
                              void* d_out, int out_size, void* d_ws, size_t ws_size,
                              hipStream_t stream) {
    const float* x            = (const float*)d_in[0];
    const int*   ei           = (const int*)d_in[1];
    const float* enc_gat_W    = (const float*)d_in[2];
    const float* enc_gat_asrc = (const float*)d_in[3];
    const float* enc_gat_adst = (const float*)d_in[4];
    const float* enc_gat_b    = (const float*)d_in[5];
    const float* enc_gcn_W    = (const float*)d_in[6];
    const float* enc_gcn_b    = (const float*)d_in[7];
    const float* densea_W     = (const float*)d_in[8];
    const float* densea_b     = (const float*)d_in[9];
    const float* latent_W     = (const float*)d_in[10];
    const float* latent_b     = (const float*)d_in[11];
    const float* dec1_W       = (const float*)d_in[12];
    const float* dec1_b       = (const float*)d_in[13];
    const float* dec2_W       = (const float*)d_in[14];
    const float* dec2_b       = (const float*)d_in[15];
    const float* dec_gcn_W    = (const float*)d_in[16];
    const float* dec_gcn_b    = (const float*)d_in[17];
    const float* dec_gat_W    = (const float*)d_in[18];
    const float* dec_gat_asrc = (const float*)d_in[19];
    const float* dec_gat_adst = (const float*)d_in[20];
    const float* dec_gat_b    = (const float*)d_in[21];

    float* out = (float*)d_out;

    // ws layout (~47 MB)
    const size_t GSZ = (size_t)NBLK * 131072;      // blocked split (K=1024 max)
    unsigned short* Xhi = (unsigned short*)d_ws;   // shared: GEMM A-splits + pdist
    unsigned short* Xlo = Xhi + GSZ;
    float*    sqn      = (float*)(Xlo + GSZ);      // 10,000
    float*    score    = sqn + 10000;              // EN*2 = 340,000
    float*    esum     = score + 340000;           // 20,000
    unsigned* emax     = (unsigned*)(esum + 20000);
    float*    als      = (float*)(emax + 20000);
    float*    ald      = als + 20000;
    int*      cnt      = (int*)(ald + 20000);
    int*      cursor   = cnt + 10000;
    int*      rowstart = cursor + 10000;           // 10,001
    float*    dinv     = (float*)(rowstart + 10001);
    int*      csr_src  = (int*)(dinv + 10000);     // 170,000
    int*      csr_eid  = csr_src + 170000;         // 170,000
    unsigned short* WtHi = (unsigned short*)(csr_eid + 170000);  // 524,288 max
    unsigned short* WtLo = WtHi + 524288;

    // big intermediates live in d_out (overwritten by pdist at the end)
    float* bufA = out;             // N*1024
    float* bufB = out + 10500000;  // N*1024  (also decoder-GAT output / pre-split feat)
    float* bufC = out + 21000000;  // N*512
    float* bufD = out + 26500000;  // N*512
    float* h128 = out + 32000000;  // N*128
    float* z64  = out + 33500000;  // N*64
    float* d128 = out + 34500000;  // N*128

    const int NT = 256;
    dim3 eb((EN_TOT + NT - 1) / NT);

    hipMemsetAsync(cnt, 0, NNODES * sizeof(int), stream);
    k_count<<<eb, NT, 0, stream>>>(ei, cnt);
    k_scan<<<1, 256, 0, stream>>>(cnt, rowstart, cursor, dinv);
    k_fill<<<eb, NT, 0, stream>>>(ei, cursor, csr_src, csr_eid);

    auto gemm = [&](const float* A, const float* W, const float* bias, float* Cc,
                    int M, int K, int Nn, int act) {
        dim3 g(Nn / 64, (M + 63) / 64);
        gemm64<<<g, 256, 0, stream>>>(A, W, bias, Cc, M, K, Nn, act);
    };
    // bf16-split MFMA GEMM (N%128==0, K%64==0): split A + split/transpose W + MFMA
    auto mgemm = [&](const float* A, const float* W, const float* bias, float* Cc,
                     int K, int Nn, int act) {
        int KC = K >> 3;
        dim3 sg(K / 64, NBLK);
        k_split_blk<<<sg, 256, 0, stream>>>(A, Xhi, Xlo, K);
        dim3 wg(KC / 2, Nn / 128);
        k_splitw<<<wg, 256, 0, stream>>>(W, WtHi, WtLo, K, Nn);
        dim3 gg(Nn / 128, NBLK);
        gemm_mfma<<<gg, 256, 0, stream>>>(Xhi, Xlo, WtHi, WtLo, bias, Cc, KC, Nn, act);
    };

    // ----- encoder GAT -----
    mgemm(x, enc_gat_W, nullptr, bufA, 512, 1024, 0);
    gat_scores<<<NNODES, 128, 0, stream>>>(bufA, enc_gat_asrc, enc_gat_adst, als, ald);
    k_init_gat<<<(2 * NNODES + 255) / 256, 256, 0, stream>>>(emax, esum);
    k_edge_score<<<eb, NT, 0, stream>>>(ei, als, ald, score, emax);
    k_edge_exp<<<eb, NT, 0, stream>>>(ei, score, emax, esum);
    gat_aggregate<<<NNODES, 256, 0, stream>>>(bufA, score, esum, rowstart, csr_src,
                                              csr_eid, enc_gat_b, bufB, 1);

    // ----- encoder GCN -----
    mgemm(bufB, enc_gcn_W, nullptr, bufC, 1024, 512, 0);
    gcn_aggregate<<<NNODES, 128, 0, stream>>>(bufC, dinv, rowstart, csr_src,
                                              enc_gcn_b, bufD, 1);

    // ----- dense encoder / decoder -----
    mgemm(bufD, densea_W, densea_b, h128, 512, 128, 1);
    gemm(h128, latent_W, latent_b, z64, NNODES, 128, 64, 0);
    gemm(z64, dec1_W, dec1_b, d128, NNODES, 64, 128, 1);
    mgemm(d128, dec2_W, dec2_b, bufC, 128, 512, 1);

    // ----- decoder GCN -----
    mgemm(bufC, dec_gcn_W, nullptr, bufD, 512, 512, 0);
    gcn_aggregate<<<NNODES, 128, 0, stream>>>(bufD, dinv, rowstart, csr_src,
                                              dec_gcn_b, bufC, 1);

    // ----- decoder GAT (no relu) -> bufB -----
    mgemm(bufC, dec_gat_W, nullptr, bufA, 512, 1024, 0);
    gat_scores<<<NNODES, 128, 0, stream>>>(bufA, dec_gat_asrc, dec_gat_adst, als, ald);
    k_init_gat<<<(2 * NNODES + 255) / 256, 256, 0, stream>>>(emax, esum);
    k_edge_score<<<eb, NT, 0, stream>>>(ei, als, ald, score, emax);
    k_edge_exp<<<eb, NT, 0, stream>>>(ei, score, emax, esum);
    gat_aggregate<<<NNODES, 256, 0, stream>>>(bufA, score, esum, rowstart, csr_src,
                                              csr_eid, dec_gat_b, bufB, 0);

    // ----- blocked split + norms, then triangular MFMA pdist -----
    dim3 sg(16, NBLK);
    k_split_blk<<<sg, 256, 0, stream>>>(bufB, Xhi, Xlo, 1024);
    k_sqn<<<NNODES, 256, 0, stream>>>(bufB, sqn);
    k_gram_pdist<<<NTRI, 256, 0, stream>>>(Xhi, Xlo, sqn, out);
}